// Round 6
// baseline (605.696 us; speedup 1.0000x reference)
//
#include <hip/hip_runtime.h>
#include <math.h>

typedef unsigned int u32;
typedef unsigned short u16;
typedef __attribute__((ext_vector_type(8))) short short8;
typedef __attribute__((ext_vector_type(4))) float float4v;

#define NBATCH 4
#define HW 65536

// ws layout (floats)
#define OFF_COV 0        // cov[8][B][64][64]   131072 floats  [0,131072)
#define OFF_T   131072   // T[10][B][64][64]    163840 floats  [131072,294912)
#define OFF_M   294912   // M[3][B][64][64]      49152 floats  [294912,344064)
#define OFF_P   344064   // P[3][B][64][64]      49152 floats  [344064,393216)
#define OFF_WC  393216   // canonical bf16 weights: 30 x 8192 u16 = 122880 floats
#define OFF_PAR 516096   // per-px LN stats {mu_i,r_i,mu_e,r_e}: 262144*4 floats
#define WS_NEED ((size_t)(OFF_PAR + 1048576) * 4)

__device__ inline float bf2f(u16 h){ return __uint_as_float(((u32)h) << 16); }
__device__ inline u16 f2bf(float x){
  u32 u = __float_as_uint(x);
  u += 0x7fffu + ((u >> 16) & 1u);
  return (u16)(u >> 16);
}
// single-instruction RNE pack of 2 f32 -> 2 bf16 (lo = a, hi = b)
__device__ inline u32 packbf2(float a, float b){
  u32 r;
  asm("v_cvt_pk_bf16_f32 %0, %1, %2" : "=v"(r) : "v"(a), "v"(b));
  return r;
}
__device__ inline float bfu(u32 u, int hi){
  return __uint_as_float(hi ? (u & 0xffff0000u) : (u << 16));
}

// Device-side dtype sniff: bf16 data has sane low-half bf16 exponents; fp32
// data's low 16 bits are mantissa noise. 256 threads vote.
__device__ inline bool detect_f32(const void* probe, int t, int* s_cnt){
  if (t == 0) *s_cnt = 0;
  __syncthreads();
  u32 w = ((const u32*)probe)[t & 255];
  u32 ex = (w >> 7) & 0xffu;
  if (!(ex >= 113u && ex <= 133u)) atomicAdd(s_cnt, 1);
  __syncthreads();
  return *s_cnt >= 128;
}

// wide-block variant: only t<256 vote, all threads read the result.
__device__ inline bool detect_f32_wide(const void* probe, int t, int* s_cnt){
  if (t == 0) *s_cnt = 0;
  __syncthreads();
  if (t < 256){
    u32 w = ((const u32*)probe)[t];
    u32 ex = (w >> 7) & 0xffu;
    if (!(ex >= 113u && ex <= 133u)) atomicAdd(s_cnt, 1);
  }
  __syncthreads();
  return *s_cnt >= 128;
}

__device__ inline void ld8(const u16* pb, const float* pf, size_t idx, bool f32, float* o){
  if (f32){
    const float4 a = *(const float4*)(pf + idx);
    const float4 b = *(const float4*)(pf + idx + 4);
    o[0]=a.x; o[1]=a.y; o[2]=a.z; o[3]=a.w; o[4]=b.x; o[5]=b.y; o[6]=b.z; o[7]=b.w;
  } else {
    uint4 r = *(const uint4*)(pb + idx);
    const u32* p = (const u32*)&r;
    #pragma unroll
    for (int j=0;j<8;j++) o[j] = bfu(p[j>>1], j&1);
  }
}

// prefetch split: issue raw 16B loads now, unpack at use
__device__ inline void ld8_issue(const u16* pb, const float* pf, size_t idx, bool f32, uint4* r2){
  if (f32){
    r2[0] = *(const uint4*)(pf + idx);
    r2[1] = *(const uint4*)(pf + idx + 4);
  } else {
    r2[0] = *(const uint4*)(pb + idx);
  }
}
__device__ inline void ld8_unpack(const uint4* r2, bool f32, float* o){
  if (f32){
    const float* q = (const float*)r2;
    #pragma unroll
    for (int j=0;j<8;j++) o[j] = q[j];
  } else {
    const u32* p = (const u32*)r2;
    #pragma unroll
    for (int j=0;j<8;j++) o[j] = bfu(p[j>>1], j&1);
  }
}

__device__ inline void softmax16(float* l){
  float m = l[0];
  #pragma unroll
  for (int i=1;i<16;i++) m = fmaxf(m, l[i]);
  float s = 0.f;
  #pragma unroll
  for (int i=0;i<16;i++){ l[i] = __expf(l[i]-m); s += l[i]; }
  float r = 1.0f/s;
  #pragma unroll
  for (int i=0;i<16;i++) l[i] *= r;
}

// ---------------------------------------------------------------------------
// convert_all: canonicalize 30 weight tensors to bf16 slots + zero cov.
// grid 32: blocks 0-29 convert, blocks 30-31 zero cov[131072 floats].
// ---------------------------------------------------------------------------
__global__ __launch_bounds__(256) void convert_all(
    const void* img,
    const void* t0, const void* t1, const void* t2, const void* t3,
    const void* t4, const void* t5, const void* t6, const void* t7,
    const void* t8, const void* t9, const void* t10, const void* t11,
    const void* t12, const void* t13, const void* t14, const void* t15,
    const void* t16, const void* t17, const void* t18, const void* t19,
    const void* t20, const void* t21, const void* t22, const void* t23,
    const void* t24, const void* t25, const void* t26, const void* t27,
    const void* t28, const void* t29,
    u16* __restrict__ wc, float* __restrict__ cov)
{
  __shared__ int s_cnt;
  const int t = threadIdx.x;
  const bool f32 = detect_f32(img, t, &s_cnt);
  const int id = blockIdx.x;
  if (id >= 30){
    float4 z; z.x=0.f; z.y=0.f; z.z=0.f; z.w=0.f;
    float4* c4 = (float4*)cov + (size_t)(id-30)*16384;
    for (int j = t; j < 16384; j += 256) c4[j] = z;
    return;
  }
  const int sizes[30] = {4096,4096,4096,4,4096,4096,4096,4,
                         64,64,64,64,64,64,64,64,64,64,64,64,
                         8192,128,8192,64,8192,128,8192,64,4096,4096};
  const void* srcs[30] = {t0,t1,t2,t3,t4,t5,t6,t7,t8,t9,t10,t11,t12,t13,t14,
                          t15,t16,t17,t18,t19,t20,t21,t22,t23,t24,t25,t26,t27,t28,t29};
  const void* s = srcs[id];
  const int n = sizes[id];
  u16* d = wc + (size_t)id*8192;
  for (int j = t; j < n; j += 256)
    d[j] = f32 ? f2bf(((const float*)s)[j]) : ((const u16*)s)[j];
}

// ---------------------------------------------------------------------------
// K1: per-pixel LN of {img, evt, img+evt, img-evt} -> 8 covariance matrices.
// 512 threads = 8 waves; ONE 64x64 Gram per wave (proven round-1 version).
// ---------------------------------------------------------------------------
__global__ __launch_bounds__(512, 4) void k1_cov(
    const void* __restrict__ img, const void* __restrict__ evt,
    const u16* __restrict__ lniw, const u16* __restrict__ lnib,
    const u16* __restrict__ lnew, const u16* __restrict__ lneb,
    const u16* __restrict__ lncw, const u16* __restrict__ lncb,
    const u16* __restrict__ lndw, const u16* __restrict__ lndb,
    float* __restrict__ cov, float* __restrict__ par, int use_par)
{
  __shared__ u16 NtL[4*64*72];
  __shared__ float spart[8][64][5];
  __shared__ float params[8][64];
  __shared__ int s_cnt;

  const int t = threadIdx.x;
  const bool f32 = detect_f32_wide(img, t, &s_cnt);
  const u16* imgb = (const u16*)img; const float* imgf = (const float*)img;
  const u16* evtb = (const u16*)evt; const float* evtf = (const float*)evt;

  const int b = blockIdx.x >> 7;
  const int P0 = (blockIdx.x & 127) * 512;
  const int ch = t >> 3, pg = t & 7;
  const int wave = t >> 6, lane = t & 63, l15 = lane & 15, quad = lane >> 4;

  float wi=bf2f(lniw[ch]), bi=bf2f(lnib[ch]);
  float we=bf2f(lnew[ch]), be=bf2f(lneb[ch]);
  float wc_=bf2f(lncw[ch]), bc_=bf2f(lncb[ch]);
  float wd_=bf2f(lndw[ch]), bd_=bf2f(lndb[ch]);

  const int va = (wave==3)?0 : (wave==7)?1 : (wave<3)?2:3;
  const int vb = (wave==0)?2 : (wave==4)?3 :
                 ((wave==2)||(wave==6)||(wave==7))?1:0;

  float4v acc[4][4];
  #pragma unroll
  for (int i=0;i<4;i++)
    #pragma unroll
    for (int j=0;j<4;j++) acc[i][j]=(float4v)0.f;

  const size_t base = (size_t)(b*64 + ch) * HW;

  for (int it = 0; it < 8; ++it){
    const int p0 = P0 + it*64;
    float A[8], B[8];
    ld8(imgb, imgf, base + p0 + pg*8, f32, A);
    ld8(evtb, evtf, base + p0 + pg*8, f32, B);

    #pragma unroll 1
    for (int jp=0;jp<4;jp++){
      float xa=A[2*jp], xb=A[2*jp+1], ea=B[2*jp], eb=B[2*jp+1];
      float s0a=xa,     s0b=xb;
      float s1a=xa*xa,  s1b=xb*xb;
      float s2a=ea,     s2b=eb;
      float s3a=ea*ea,  s3b=eb*eb;
      float s4a=xa*ea,  s4b=xb*eb;
      #pragma unroll
      for (int m=8;m<=32;m<<=1){
        s0a+=__shfl_xor(s0a,m); s0b+=__shfl_xor(s0b,m);
        s1a+=__shfl_xor(s1a,m); s1b+=__shfl_xor(s1b,m);
        s2a+=__shfl_xor(s2a,m); s2b+=__shfl_xor(s2b,m);
        s3a+=__shfl_xor(s3a,m); s3b+=__shfl_xor(s3b,m);
        s4a+=__shfl_xor(s4a,m); s4b+=__shfl_xor(s4b,m);
      }
      if ((ch&7)==0){
        int px = pg*8 + 2*jp;
        spart[wave][px][0]=s0a; spart[wave][px][1]=s1a; spart[wave][px][2]=s2a;
        spart[wave][px][3]=s3a; spart[wave][px][4]=s4a;
        spart[wave][px+1][0]=s0b; spart[wave][px+1][1]=s1b; spart[wave][px+1][2]=s2b;
        spart[wave][px+1][3]=s3b; spart[wave][px+1][4]=s4b;
      }
    }
    __syncthreads();
    if (t < 64){
      float S0=0,S1=0,S2=0,S3=0,S4=0;
      #pragma unroll
      for (int w=0;w<8;w++){
        S0+=spart[w][t][0]; S1+=spart[w][t][1]; S2+=spart[w][t][2];
        S3+=spart[w][t][3]; S4+=spart[w][t][4];
      }
      const float inv = 0.015625f;
      float mu_i=S0*inv, mu_e=S2*inv;
      float r_i = rsqrtf(fmaf(S1,inv,-mu_i*mu_i)+1e-5f);
      float r_e = rsqrtf(fmaf(S3,inv,-mu_e*mu_e)+1e-5f);
      float mu_c=mu_i+mu_e, mu_d=mu_i-mu_e;
      float r_c = rsqrtf((S1+2.f*S4+S3)*inv - mu_c*mu_c + 1e-5f);
      float r_d = rsqrtf((S1-2.f*S4+S3)*inv - mu_d*mu_d + 1e-5f);
      params[0][t]=mu_i; params[1][t]=r_i; params[2][t]=mu_e; params[3][t]=r_e;
      params[4][t]=mu_c; params[5][t]=r_c; params[6][t]=mu_d; params[7][t]=r_d;
      if (use_par){
        float4 pv; pv.x=mu_i; pv.y=r_i; pv.z=mu_e; pv.w=r_e;
        *(float4*)(par + ((size_t)b*HW + p0 + t)*4) = pv;
      }
    }
    __syncthreads();

    {
      u32 u0[4], u1[4];
      #pragma unroll
      for (int jj=0;jj<4;jj++){
        int px = pg*8 + 2*jj;
        float2 mi01 = *(const float2*)&params[0][px];
        float2 ri01 = *(const float2*)&params[1][px];
        float2 me01 = *(const float2*)&params[2][px];
        float2 re01 = *(const float2*)&params[3][px];
        u0[jj] = packbf2(fmaf((A[2*jj]-mi01.x)*ri01.x, wi, bi),
                         fmaf((A[2*jj+1]-mi01.y)*ri01.y, wi, bi));
        u1[jj] = packbf2(fmaf((B[2*jj]-me01.x)*re01.x, we, be),
                         fmaf((B[2*jj+1]-me01.y)*re01.y, we, be));
      }
      *(uint4*)&NtL[(0*64+ch)*72 + pg*8] = make_uint4(u0[0],u0[1],u0[2],u0[3]);
      *(uint4*)&NtL[(1*64+ch)*72 + pg*8] = make_uint4(u1[0],u1[1],u1[2],u1[3]);
      #pragma unroll
      for (int jj=0;jj<4;jj++){
        int px = pg*8 + 2*jj;
        float2 mc01 = *(const float2*)&params[4][px];
        float2 rc01 = *(const float2*)&params[5][px];
        float2 md01 = *(const float2*)&params[6][px];
        float2 rd01 = *(const float2*)&params[7][px];
        float xc0=A[2*jj]+B[2*jj], xc1=A[2*jj+1]+B[2*jj+1];
        float xd0=A[2*jj]-B[2*jj], xd1=A[2*jj+1]-B[2*jj+1];
        u0[jj] = packbf2(fmaf((xc0-mc01.x)*rc01.x, wc_, bc_),
                         fmaf((xc1-mc01.y)*rc01.y, wc_, bc_));
        u1[jj] = packbf2(fmaf((xd0-md01.x)*rd01.x, wd_, bd_),
                         fmaf((xd1-md01.y)*rd01.y, wd_, bd_));
      }
      *(uint4*)&NtL[(2*64+ch)*72 + pg*8] = make_uint4(u0[0],u0[1],u0[2],u0[3]);
      *(uint4*)&NtL[(3*64+ch)*72 + pg*8] = make_uint4(u1[0],u1[1],u1[2],u1[3]);
    }
    __syncthreads();

    #pragma unroll
    for (int ks=0; ks<2; ks++){
      const int off = ks*32 + quad*8;
      short8 Af[4], Bf[4];
      #pragma unroll
      for (int mi=0;mi<4;mi++){
        Af[mi] = *(const short8*)&NtL[(va*64 + mi*16 + l15)*72 + off];
        Bf[mi] = *(const short8*)&NtL[(vb*64 + mi*16 + l15)*72 + off];
      }
      #pragma unroll
      for (int mi=0;mi<4;mi++)
        #pragma unroll
        for (int nj=0;nj<4;nj++)
          acc[mi][nj] = __builtin_amdgcn_mfma_f32_16x16x32_bf16(Af[mi], Bf[nj], acc[mi][nj], 0,0,0);
    }
  }
  float* cg = cov + ((size_t)wave*NBATCH + b)*4096;
  #pragma unroll
  for (int mi=0;mi<4;mi++)
    #pragma unroll
    for (int nj=0;nj<4;nj++){
      int row0 = mi*16 + quad*4, col = nj*16 + l15;
      #pragma unroll
      for (int r=0;r<4;r++)
        atomicAdd(&cg[(row0+r)*64 + col], acc[mi][nj][r]);
    }
}

// ---------------------------------------------------------------------------
// P2 fused: phase A = 10 T-GEMMs; phase B = norms/softmax/M; phase C = 3 P-GEMMs.
// grid 4 (one block per batch), 256 threads. Within-block global R-after-W is
// fenced by __syncthreads.
// ---------------------------------------------------------------------------
__global__ __launch_bounds__(256) void p2_fused(
    const u16* __restrict__ Wq_c, const u16* __restrict__ Wk_c,
    const u16* __restrict__ Wq_d, const u16* __restrict__ Wk_d,
    const u16* __restrict__ Wv_c, const u16* __restrict__ Wv_d,
    const u16* __restrict__ temp_c, const u16* __restrict__ temp_d,
    const u16* __restrict__ proj1, const u16* __restrict__ proj2,
    float* __restrict__ ws)
{
  __shared__ float WL[64][65];
  __shared__ float CL[64][64];
  __shared__ float rn[6][64];
  __shared__ float GLs[4][64][16];
  __shared__ float AL[3][64][16];
  const int t = threadIdx.x;
  const int b = blockIdx.x;

  // ---- phase A: T[which] = W @ C[csel] ----
  const int wsel_tab[10] = {0,1,1,2,3,3,0,0,2,2};
  const int csel_tab[10] = {0,3,7,4,3,7,1,2,5,6};
  #pragma unroll 1
  for (int which=0; which<10; ++which){
    const int wsel = wsel_tab[which], csel = csel_tab[which];
    const u16* W = (wsel==0)? Wq_c : (wsel==1)? Wk_c : (wsel==2)? Wq_d : Wk_d;
    const float* Cm = ws + ((size_t)csel*NBATCH + b)*4096;
    __syncthreads();
    { int r = t>>2, c0 = (t&3)*16;
      #pragma unroll
      for (int i=0;i<16;i++) WL[r][c0+i] = bf2f(W[r*64 + c0 + i]);
      const float4* s = (const float4*)(Cm + r*64 + c0);
      float4* d = (float4*)&CL[r][c0];
      d[0]=s[0]; d[1]=s[1]; d[2]=s[2]; d[3]=s[3]; }
    __syncthreads();
    const int r = t>>2, k0 = (t&3)*16;
    float a[16];
    #pragma unroll
    for (int i=0;i<16;i++) a[i]=0.f;
    for (int m=0;m<64;m++){
      float wv = WL[r][m];
      #pragma unroll
      for (int i=0;i<16;i++) a[i] = fmaf(wv, CL[m][k0+i], a[i]);
    }
    float* o = ws + OFF_T + ((size_t)which*NBATCH + b)*4096 + r*64 + k0;
    #pragma unroll
    for (int i=0;i<16;i++) o[i] = a[i];
  }
  __syncthreads();

  // ---- phase B: norms, Gram blocks, softmax, A, M ----
  const float* T = ws + OFF_T;
  {
    int s = t>>6, c = t&63;
    const float* Tp = T + ((size_t)s*NBATCH + b)*4096 + c*64;
    const u16* Wp = (s==0)? Wq_c : (s==3)? Wq_d : Wk_c;
    float acc=0;
    for (int k=0;k<64;k++) acc = fmaf(Tp[k], bf2f(Wp[c*64+k]), acc);
    rn[s][c] = 1.0f/fmaxf(sqrtf(fmaxf(acc,0.f)), 1e-12f);
    if (t < 128){
      int s2 = 4 + (t>>6);
      const float* Tp2 = T + ((size_t)s2*NBATCH + b)*4096 + c*64;
      float acc2=0;
      for (int k=0;k<64;k++) acc2 = fmaf(Tp2[k], bf2f(Wk_d[c*64+k]), acc2);
      rn[s2][c] = 1.0f/fmaxf(sqrtf(fmaxf(acc2,0.f)), 1e-12f);
    }
  }
  #pragma unroll 1
  for (int i=0;i<16;i++){
    int e = t*16 + i;
    int s = e >> 10, c = (e>>4)&63, dl = e&15, d = (c&~15)+dl;
    const float* Tp = T + ((size_t)(6+s)*NBATCH + b)*4096 + c*64;
    const u16* Wp = ((s<2)? Wk_c : Wk_d) + d*64;
    float acc=0;
    for (int j=0;j<64;j++) acc = fmaf(Tp[j], bf2f(Wp[j]), acc);
    GLs[s][c][dl] = acc;
  }
  __syncthreads();
  if (t < 192){
    int set = t>>6, c = t&63, h = c>>4, cb = c&~15;
    if (set == 0){
      float tc = bf2f(temp_c[h]);
      float rq = rn[0][c];
      float l1[16], l2[16];
      #pragma unroll
      for (int dl=0;dl<16;dl++){
        l1[dl] = GLs[0][c][dl]*rq*rn[1][cb+dl]*tc;
        l2[dl] = GLs[1][c][dl]*rq*rn[2][cb+dl]*tc;
      }
      softmax16(l1); softmax16(l2);
      #pragma unroll
      for (int dl=0;dl<16;dl++) AL[0][c][dl] = l1[dl]*l2[dl];
    } else {
      float td = bf2f(temp_d[h]);
      float rq = rn[3][c];
      int gi = (set==1)? 2 : 3;
      int rk = (set==1)? 4 : 5;
      float l[16];
      #pragma unroll
      for (int dl=0;dl<16;dl++) l[dl] = GLs[gi][c][dl]*rq*rn[rk][cb+dl]*td;
      softmax16(l);
      #pragma unroll
      for (int dl=0;dl<16;dl++) AL[set][c][dl] = l[dl];
    }
  }
  __syncthreads();
  for (int wsel=0; wsel<3; wsel++){
    const u16* Wv = (wsel==0)? Wv_c : Wv_d;
    #pragma unroll 1
    for (int i=0;i<16;i++){
      int e = t*16+i, c = e>>6, k = e&63, cb = c&~15;
      float acc=0;
      #pragma unroll
      for (int dl=0;dl<16;dl++) acc = fmaf(AL[wsel][c][dl], bf2f(Wv[(cb+dl)*64 + k]), acc);
      ws[OFF_M + ((size_t)wsel*NBATCH + b)*4096 + c*64 + k] = acc;
    }
  }
  __syncthreads();

  // ---- phase C: P[which] = proj @ M[which] ----
  #pragma unroll 1
  for (int which=0; which<3; ++which){
    const u16* W = (which==0)? proj1 : proj2;
    const float* Cm = ws + OFF_M + ((size_t)which*NBATCH + b)*4096;
    __syncthreads();
    { int r = t>>2, c0 = (t&3)*16;
      #pragma unroll
      for (int i=0;i<16;i++) WL[r][c0+i] = bf2f(W[r*64 + c0 + i]);
      const float4* s = (const float4*)(Cm + r*64 + c0);
      float4* d = (float4*)&CL[r][c0];
      d[0]=s[0]; d[1]=s[1]; d[2]=s[2]; d[3]=s[3]; }
    __syncthreads();
    const int r = t>>2, k0 = (t&3)*16;
    float a[16];
    #pragma unroll
    for (int i=0;i<16;i++) a[i]=0.f;
    for (int m=0;m<64;m++){
      float wv = WL[r][m];
      #pragma unroll
      for (int i=0;i<16;i++) a[i] = fmaf(wv, CL[m][k0+i], a[i]);
    }
    float* o = ws + OFF_P + ((size_t)which*NBATCH + b)*4096 + r*64 + k0;
    #pragma unroll
    for (int i=0;i<16;i++) o[i] = a[i];
  }
}

// ---------------------------------------------------------------------------
// K3 fat: one dispatch for BOTH branches. grid 2048, 256 threads.
// Even blocks: common branch; odd blocks: diff branch — adjacent blocks share
// the SAME 256-px slab of img/evt/par -> L2 reuse. LDS hand-carved from one
// pool (union of both branches, 78.6 KB -> 2 blocks/CU, 1 common + 1 diff).
// Bodies are the round-4 proven versions (incl. next-iter prefetch).
// ---------------------------------------------------------------------------
__global__ __launch_bounds__(256, 2) void k3_fat(
    const void* __restrict__ img, const void* __restrict__ evt,
    const u16* __restrict__ lniw, const u16* __restrict__ lnib,
    const u16* __restrict__ lnew, const u16* __restrict__ lneb,
    const u16* __restrict__ ln1w, const u16* __restrict__ ln1b,
    const u16* __restrict__ ln2w, const u16* __restrict__ ln2b,
    const u16* __restrict__ fc1cw, const u16* __restrict__ fc1cb,
    const u16* __restrict__ fc2cw, const u16* __restrict__ fc2cb,
    const u16* __restrict__ fc1dw, const u16* __restrict__ fc1db,
    const u16* __restrict__ fc2dw, const u16* __restrict__ fc2db,
    const float* __restrict__ Pmat, void* __restrict__ outp,
    const float* __restrict__ par, int use_par)
{
  __shared__ __align__(16) u16 POOL[36352];   // 72704 B
  __shared__ float spart[4][64][4];
  __shared__ float params[64][4];
  __shared__ float b1L[128];
  __shared__ float b2L[64];
  __shared__ int s_cnt;

  u16* fc1L = POOL;            // 128*72
  u16* fc2L = POOL + 9216;     // 64*136
  u16* P0L  = POOL + 17920;    // 64*72 (PcL / PiL)
  u16* P1L  = POOL + 22528;    // 64*72 (PeL)
  u16* BIG  = POOL + 27136;    // 64*144 (SB stride 136 / N2L stride 144)

  const int t = threadIdx.x;
  const bool f32 = detect_f32(img, t, &s_cnt);
  const u16* imgb = (const u16*)img; const float* imgf = (const float*)img;
  const u16* evtb = (const u16*)evt; const float* evtf = (const float*)evt;

  const int isdiff = blockIdx.x & 1;
  const int g = blockIdx.x >> 1;          // 0..1023
  const int b = g >> 8;
  const int P0 = (g & 255) * 256;
  const size_t obase = isdiff ? (size_t)16777216 : (size_t)0;
  const int chg = t >> 3, pg = t & 7, ch0 = chg*2;
  const int wave = t >> 6, lane = t & 63, l15 = lane & 15, quad = lane >> 4;

  // ---- shared weight staging (fc1/fc2 per branch) ----
  const u16* fc1w = isdiff ? fc1dw : fc1cw;
  const u16* fc1b = isdiff ? fc1db : fc1cb;
  const u16* fc2w = isdiff ? fc2dw : fc2cw;
  const u16* fc2b = isdiff ? fc2db : fc2cb;
  const u16* lnfw = isdiff ? ln2w : ln1w;
  const u16* lnfb = isdiff ? ln2b : ln1b;

  { int row = t >> 1, c0 = (t & 1)*32;
    const uint4* s = (const uint4*)(fc1w + row*64 + c0);
    uint4* d = (uint4*)&fc1L[row*72 + c0];
    d[0]=s[0]; d[1]=s[1]; d[2]=s[2]; d[3]=s[3]; }
  { int row = t >> 2, c0 = (t & 3)*32;
    const uint4* s = (const uint4*)(fc2w + row*128 + c0);
    uint4* d = (uint4*)&fc2L[row*136 + c0];
    d[0]=s[0]; d[1]=s[1]; d[2]=s[2]; d[3]=s[3]; }
  if (!isdiff){
    int row = t >> 2, c0 = (t & 3)*16;
    const float* s = Pmat + (size_t)b*4096 + row*64 + c0;
    u32 u[8];
    #pragma unroll
    for (int i=0;i<8;i++) u[i] = packbf2(s[2*i], s[2*i+1]);
    uint4* d = (uint4*)&P0L[row*72 + c0];
    d[0] = make_uint4(u[0],u[1],u[2],u[3]);
    d[1] = make_uint4(u[4],u[5],u[6],u[7]);
  } else {
    int row = t >> 2, c0 = (t & 3)*16;
    const float* si_ = Pmat + ((size_t)1*NBATCH + b)*4096 + row*64 + c0;
    const float* se_ = Pmat + ((size_t)2*NBATCH + b)*4096 + row*64 + c0;
    u32 u[8];
    #pragma unroll
    for (int i=0;i<8;i++) u[i] = packbf2(si_[2*i], si_[2*i+1]);
    uint4* d = (uint4*)&P0L[row*72 + c0];
    d[0] = make_uint4(u[0],u[1],u[2],u[3]); d[1] = make_uint4(u[4],u[5],u[6],u[7]);
    #pragma unroll
    for (int i=0;i<8;i++) u[i] = packbf2(se_[2*i], se_[2*i+1]);
    uint4* d2 = (uint4*)&P1L[row*72 + c0];
    d2[0] = make_uint4(u[0],u[1],u[2],u[3]); d2[1] = make_uint4(u[4],u[5],u[6],u[7]);
  }
  if (t < 128) b1L[t] = bf2f(fc1b[t]);
  if (t < 64)  b2L[t] = bf2f(fc2b[t]);

  // LN-in weights (common folds i+e bias; diff keeps separate)
  float wi0=bf2f(lniw[ch0]), wi1=bf2f(lniw[ch0+1]);
  float we0=bf2f(lnew[ch0]), we1=bf2f(lnew[ch0+1]);
  float bi0=bf2f(lnib[ch0]), bi1=bf2f(lnib[ch0+1]);
  float be0=bf2f(lneb[ch0]), be1=bf2f(lneb[ch0+1]);
  float bs0=bi0+be0, bs1=bi1+be1;
  float w1r[4], b1r[4];
  #pragma unroll
  for (int nj=0;nj<4;nj++){ w1r[nj]=bf2f(lnfw[nj*16+l15]); b1r[nj]=bf2f(lnfb[nj*16+l15]); }

  const size_t base_i = (size_t)(b*64 + ch0)*HW;
  uint4 rA0[2], rA1[2], rB0[2], rB1[2];
  float4 PR[8];
  if (use_par){
    ld8_issue(imgb, imgf, base_i + P0 + pg*8, f32, rA0);
    ld8_issue(imgb, imgf, base_i + HW + P0 + pg*8, f32, rA1);
    ld8_issue(evtb, evtf, base_i + P0 + pg*8, f32, rB0);
    ld8_issue(evtb, evtf, base_i + HW + P0 + pg*8, f32, rB1);
    const float4* pp = (const float4*)(par + ((size_t)b*HW + P0 + pg*8)*4);
    #pragma unroll
    for (int j=0;j<8;j++) PR[j] = pp[j];
  }
  __syncthreads();

  const int STRIDE = isdiff ? 144 : 136;
  for (int it=0; it<4; ++it){
    const int p0 = P0 + it*64;
    // ---- n-hat production into BIG ----
    if (use_par){
      float A0[8], A1[8], B0[8], B1[8];
      ld8_unpack(rA0, f32, A0); ld8_unpack(rA1, f32, A1);
      ld8_unpack(rB0, f32, B0); ld8_unpack(rB1, f32, B1);
      if (!isdiff){
        #pragma unroll
        for (int j=0;j<8;j++){
          float4 pr = PR[j];
          float a0=(A0[j]-pr.x)*pr.y, a1=(A1[j]-pr.x)*pr.y;
          float c0f=(B0[j]-pr.z)*pr.w, c1f=(B1[j]-pr.z)*pr.w;
          float n0 = fmaf(a0, wi0, fmaf(c0f, we0, bs0));
          float n1 = fmaf(a1, wi1, fmaf(c1f, we1, bs1));
          *(u32*)&BIG[(pg*8+j)*136 + ch0] = packbf2(n0, n1);
        }
      } else {
        #pragma unroll
        for (int j=0;j<8;j++){
          float4 pr = PR[j];
          float a0=(A0[j]-pr.x)*pr.y, a1=(A1[j]-pr.x)*pr.y;
          float c0f=(B0[j]-pr.z)*pr.w, c1f=(B1[j]-pr.z)*pr.w;
          *(u32*)&BIG[(pg*8+j)*144 + ch0]      = packbf2(fmaf(a0,wi0,bi0), fmaf(a1,wi1,bi1));
          *(u32*)&BIG[(pg*8+j)*144 + 72 + ch0] = packbf2(fmaf(c0f,we0,be0), fmaf(c1f,we1,be1));
        }
      }
    } else {
      float A0[8], A1[8], B0[8], B1[8];
      ld8(imgb, imgf, base_i + p0 + pg*8, f32, A0);
      ld8(imgb, imgf, base_i + HW + p0 + pg*8, f32, A1);
      ld8(evtb, evtf, base_i + p0 + pg*8, f32, B0);
      ld8(evtb, evtf, base_i + HW + p0 + pg*8, f32, B1);
      float si[8], sii[8], se[8], see[8];
      #pragma unroll
      for (int j=0;j<8;j++){
        float xi0=A0[j], xi1=A1[j], xe0=B0[j], xe1=B1[j];
        si[j]=xi0+xi1; sii[j]=fmaf(xi0,xi0,xi1*xi1);
        se[j]=xe0+xe1; see[j]=fmaf(xe0,xe0,xe1*xe1);
      }
      #pragma unroll
      for (int m=8;m<=32;m<<=1)
        #pragma unroll
        for (int j=0;j<8;j++){
          si[j]+=__shfl_xor(si[j],m); sii[j]+=__shfl_xor(sii[j],m);
          se[j]+=__shfl_xor(se[j],m); see[j]+=__shfl_xor(see[j],m);
        }
      if ((chg&7)==0){
        #pragma unroll
        for (int j=0;j<8;j++){
          spart[wave][pg*8+j][0]=si[j]; spart[wave][pg*8+j][1]=sii[j];
          spart[wave][pg*8+j][2]=se[j]; spart[wave][pg*8+j][3]=see[j];
        }
      }
      __syncthreads();
      if (t<64){
        float S0=0,S1=0,S2=0,S3=0;
        #pragma unroll
        for (int w=0;w<4;w++){ S0+=spart[w][t][0]; S1+=spart[w][t][1]; S2+=spart[w][t][2]; S3+=spart[w][t][3]; }
        const float inv=0.015625f;
        float mu_i=S0*inv, mu_e=S2*inv;
        float r_i=rsqrtf(fmaf(S1,inv,-mu_i*mu_i)+1e-5f);
        float r_e=rsqrtf(fmaf(S3,inv,-mu_e*mu_e)+1e-5f);
        params[t][0]=mu_i; params[t][1]=r_i; params[t][2]=mu_e; params[t][3]=r_e;
      }
      __syncthreads();
      if (!isdiff){
        #pragma unroll
        for (int j=0;j<8;j++){
          float4 pr = *(const float4*)&params[pg*8+j][0];
          float a0=(A0[j]-pr.x)*pr.y, a1=(A1[j]-pr.x)*pr.y;
          float c0f=(B0[j]-pr.z)*pr.w, c1f=(B1[j]-pr.z)*pr.w;
          float n0 = fmaf(a0, wi0, fmaf(c0f, we0, bs0));
          float n1 = fmaf(a1, wi1, fmaf(c1f, we1, bs1));
          *(u32*)&BIG[(pg*8+j)*136 + ch0] = packbf2(n0, n1);
        }
      } else {
        #pragma unroll
        for (int j=0;j<8;j++){
          float4 pr = *(const float4*)&params[pg*8+j][0];
          float a0=(A0[j]-pr.x)*pr.y, a1=(A1[j]-pr.x)*pr.y;
          float c0f=(B0[j]-pr.z)*pr.w, c1f=(B1[j]-pr.z)*pr.w;
          *(u32*)&BIG[(pg*8+j)*144 + ch0]      = packbf2(fmaf(a0,wi0,bi0), fmaf(a1,wi1,bi1));
          *(u32*)&BIG[(pg*8+j)*144 + 72 + ch0] = packbf2(fmaf(c0f,we0,be0), fmaf(c1f,we1,be1));
        }
      }
    }
    __syncthreads();
    // issue next-iter raw loads: drained at END barrier, hidden under compute
    if (use_par && it < 3){
      const int pn = p0 + 64;
      ld8_issue(imgb, imgf, base_i + pn + pg*8, f32, rA0);
      ld8_issue(imgb, imgf, base_i + HW + pn + pg*8, f32, rA1);
      ld8_issue(evtb, evtf, base_i + pn + pg*8, f32, rB0);
      ld8_issue(evtb, evtf, base_i + HW + pn + pg*8, f32, rB1);
      const float4* pp = (const float4*)(par + ((size_t)b*HW + pn + pg*8)*4);
      #pragma unroll
      for (int j=0;j<8;j++) PR[j] = pp[j];
    }
    // ---- GEMM1 ----
    float4v acc1[4];
    #pragma unroll
    for (int nj=0;nj<4;nj++) acc1[nj]=(float4v)0.f;
    const int px_row = wave*16 + l15;
    if (!isdiff){
      #pragma unroll
      for (int ks=0;ks<2;ks++){
        const int off = ks*32 + quad*8;
        short8 af = *(const short8*)&BIG[px_row*136 + off];
        #pragma unroll
        for (int nj=0;nj<4;nj++){
          short8 bw = *(const short8*)&P0L[(nj*16+l15)*72 + off];
          acc1[nj] = __builtin_amdgcn_mfma_f32_16x16x32_bf16(af, bw, acc1[nj], 0,0,0);
        }
      }
    } else {
      #pragma unroll
      for (int ks=0;ks<2;ks++){
        const int off = ks*32 + quad*8;
        short8 ai = *(const short8*)&BIG[px_row*144 + off];
        short8 ae = *(const short8*)&BIG[px_row*144 + 72 + off];
        #pragma unroll
        for (int nj=0;nj<4;nj++){
          short8 bwi = *(const short8*)&P0L[(nj*16+l15)*72 + off];
          acc1[nj] = __builtin_amdgcn_mfma_f32_16x16x32_bf16(ai, bwi, acc1[nj], 0,0,0);
          short8 bwe = *(const short8*)&P1L[(nj*16+l15)*72 + off];
          acc1[nj] = __builtin_amdgcn_mfma_f32_16x16x32_bf16(ae, bwe, acc1[nj], 0,0,0);
        }
      }
    }
    // ---- LN over 64 channels ----
    float s[4], sq[4];
    #pragma unroll
    for (int j=0;j<4;j++){
      s[j] = acc1[0][j]+acc1[1][j]+acc1[2][j]+acc1[3][j];
      sq[j] = acc1[0][j]*acc1[0][j];
      sq[j] = fmaf(acc1[1][j],acc1[1][j],sq[j]);
      sq[j] = fmaf(acc1[2][j],acc1[2][j],sq[j]);
      sq[j] = fmaf(acc1[3][j],acc1[3][j],sq[j]);
    }
    #pragma unroll
    for (int m=1;m<=8;m<<=1)
      #pragma unroll
      for (int j=0;j<4;j++){ s[j]+=__shfl_xor(s[j],m); sq[j]+=__shfl_xor(sq[j],m); }
    float muj[4], rj[4];
    #pragma unroll
    for (int j=0;j<4;j++){
      muj[j]=s[j]*0.015625f;
      rj[j]=rsqrtf(fmaf(sq[j],0.015625f,-muj[j]*muj[j])+1e-5f);
    }
    #pragma unroll
    for (int nj=0;nj<4;nj++)
      #pragma unroll
      for (int j=0;j<4;j++){
        float tv = (acc1[nj][j]-muj[j])*rj[j];
        tv = fmaf(tv, w1r[nj], b1r[nj]);
        BIG[(wave*16+quad*4+j)*STRIDE + nj*16+l15] = f2bf(tv);
      }
    // ---- FFN1 + GELU ----
    float4v accF[8];
    #pragma unroll
    for (int nh=0;nh<8;nh++) accF[nh]=(float4v)0.f;
    #pragma unroll
    for (int ks=0;ks<2;ks++){
      const int off = ks*32+quad*8;
      short8 af = *(const short8*)&BIG[px_row*STRIDE + off];
      #pragma unroll
      for (int nh=0;nh<8;nh++){
        short8 bw = *(const short8*)&fc1L[(nh*16+l15)*72 + off];
        accF[nh] = __builtin_amdgcn_mfma_f32_16x16x32_bf16(af, bw, accF[nh], 0,0,0);
      }
    }
    #pragma unroll
    for (int nh=0;nh<8;nh++){
      float bb = b1L[nh*16+l15];
      #pragma unroll
      for (int j=0;j<4;j++){
        float v = accF[nh][j] + bb;
        float g2 = 0.5f*v*(1.0f + erff(v*0.70710678118654752f));
        BIG[(wave*16+quad*4+j)*STRIDE + nh*16+l15] = f2bf(g2);
      }
    }
    // ---- FFN2 + residual + store ----
    float4v accO[4];
    #pragma unroll
    for (int nj=0;nj<4;nj++) accO[nj]=(float4v)0.f;
    #pragma unroll
    for (int ks=0;ks<4;ks++){
      const int off = ks*32+quad*8;
      short8 ag = *(const short8*)&BIG[px_row*STRIDE + off];
      #pragma unroll
      for (int nj=0;nj<4;nj++){
        short8 bw = *(const short8*)&fc2L[(nj*16+l15)*136 + off];
        accO[nj] = __builtin_amdgcn_mfma_f32_16x16x32_bf16(ag, bw, accO[nj], 0,0,0);
      }
    }
    const int px0 = p0 + wave*16 + quad*4;
    #pragma unroll
    for (int nj=0;nj<4;nj++){
      float bb = b2L[nj*16+l15];
      int r = nj*16+l15;
      float v0 = acc1[nj][0] + accO[nj][0] + bb;
      float v1 = acc1[nj][1] + accO[nj][1] + bb;
      float v2 = acc1[nj][2] + accO[nj][2] + bb;
      float v3 = acc1[nj][3] + accO[nj][3] + bb;
      size_t oi = obase + (size_t)(b*64 + r)*HW + px0;
      if (f32){ float4 fv; fv.x=v0; fv.y=v1; fv.z=v2; fv.w=v3;
        *(float4*)((float*)outp + oi) = fv; }
      else *(uint2*)((u16*)outp + oi) = make_uint2(packbf2(v0,v1), packbf2(v2,v3));
    }
    __syncthreads();   // protects BIG + drains prefetch loads (hidden by compute)
  }
}

extern "C" void kernel_launch(void* const* d_in, const int* in_sizes, int n_in,
                              void* d_out, int out_size, void* d_ws, size_t ws_size,
                              hipStream_t stream)
{
  const void* img = d_in[0];
  const void* evt = d_in[1];
  float* ws = (float*)d_ws;
  u16* wc = (u16*)(ws + OFF_WC);
  float* par = ws + OFF_PAR;
  const int use_par = (ws_size >= WS_NEED) ? 1 : 0;
  #define SLOT(i) (wc + (size_t)((i)-2)*8192)

  convert_all<<<dim3(32), dim3(256), 0, stream>>>(img,
      d_in[2], d_in[3], d_in[4], d_in[5], d_in[6], d_in[7], d_in[8], d_in[9],
      d_in[10], d_in[11], d_in[12], d_in[13], d_in[14], d_in[15], d_in[16], d_in[17],
      d_in[18], d_in[19], d_in[20], d_in[21], d_in[22], d_in[23], d_in[24], d_in[25],
      d_in[26], d_in[27], d_in[28], d_in[29], d_in[30], d_in[31], wc, ws);
  k1_cov<<<dim3(512), dim3(512), 0, stream>>>(img, evt,
      SLOT(10), SLOT(11), SLOT(12), SLOT(13), SLOT(14), SLOT(15), SLOT(16), SLOT(17),
      ws, par, use_par);
  p2_fused<<<dim3(4), dim3(256), 0, stream>>>(
      SLOT(2), SLOT(3), SLOT(6), SLOT(7), SLOT(4), SLOT(8), SLOT(5), SLOT(9),
      SLOT(30), SLOT(31), ws);
  k3_fat<<<dim3(2048), dim3(256), 0, stream>>>(img, evt,
      SLOT(10), SLOT(11), SLOT(12), SLOT(13),
      SLOT(18), SLOT(19), SLOT(20), SLOT(21),
      SLOT(22), SLOT(23), SLOT(24), SLOT(25),
      SLOT(26), SLOT(27), SLOT(28), SLOT(29),
      ws + OFF_P, d_out, par, use_par);
  #undef SLOT
}

// Round 7
// 560.087 us; speedup vs baseline: 1.0814x; 1.0814x over previous
//
#include <hip/hip_runtime.h>
#include <math.h>

typedef unsigned int u32;
typedef unsigned short u16;
typedef __attribute__((ext_vector_type(8))) short short8;
typedef __attribute__((ext_vector_type(4))) float float4v;

#define NBATCH 4
#define HW 65536

// ws layout (floats)
#define OFF_COV 0        // cov[8][B][64][64]   131072 floats  [0,131072)
#define OFF_T   131072   // T[10][B][64][64]    163840 floats  [131072,294912)
#define OFF_M   294912   // M[3][B][64][64]      49152 floats  [294912,344064)
#define OFF_P   344064   // P[3][B][64][64]      49152 floats  [344064,393216)
#define OFF_WC  393216   // canonical bf16 weights: 30 x 8192 u16 = 122880 floats
#define OFF_PAR 516096   // per-px LN stats {mu_i,r_i,mu_e,r_e}: 262144*4 floats
#define WS_NEED ((size_t)(OFF_PAR + 1048576) * 4)

__device__ inline float bf2f(u16 h){ return __uint_as_float(((u32)h) << 16); }
__device__ inline u16 f2bf(float x){
  u32 u = __float_as_uint(x);
  u += 0x7fffu + ((u >> 16) & 1u);
  return (u16)(u >> 16);
}
// single-instruction RNE pack of 2 f32 -> 2 bf16 (lo = a, hi = b)
__device__ inline u32 packbf2(float a, float b){
  u32 r;
  asm("v_cvt_pk_bf16_f32 %0, %1, %2" : "=v"(r) : "v"(a), "v"(b));
  return r;
}
__device__ inline float bfu(u32 u, int hi){
  return __uint_as_float(hi ? (u & 0xffff0000u) : (u << 16));
}

// Device-side dtype sniff: bf16 data has sane low-half bf16 exponents; fp32
// data's low 16 bits are mantissa noise. 256 threads vote.
__device__ inline bool detect_f32(const void* probe, int t, int* s_cnt){
  if (t == 0) *s_cnt = 0;
  __syncthreads();
  u32 w = ((const u32*)probe)[t & 255];
  u32 ex = (w >> 7) & 0xffu;
  if (!(ex >= 113u && ex <= 133u)) atomicAdd(s_cnt, 1);
  __syncthreads();
  return *s_cnt >= 128;
}

// wide-block variant: only t<256 vote, all threads read the result.
__device__ inline bool detect_f32_wide(const void* probe, int t, int* s_cnt){
  if (t == 0) *s_cnt = 0;
  __syncthreads();
  if (t < 256){
    u32 w = ((const u32*)probe)[t];
    u32 ex = (w >> 7) & 0xffu;
    if (!(ex >= 113u && ex <= 133u)) atomicAdd(s_cnt, 1);
  }
  __syncthreads();
  return *s_cnt >= 128;
}

__device__ inline void ld8(const u16* pb, const float* pf, size_t idx, bool f32, float* o){
  if (f32){
    const float4 a = *(const float4*)(pf + idx);
    const float4 b = *(const float4*)(pf + idx + 4);
    o[0]=a.x; o[1]=a.y; o[2]=a.z; o[3]=a.w; o[4]=b.x; o[5]=b.y; o[6]=b.z; o[7]=b.w;
  } else {
    uint4 r = *(const uint4*)(pb + idx);
    const u32* p = (const u32*)&r;
    #pragma unroll
    for (int j=0;j<8;j++) o[j] = bfu(p[j>>1], j&1);
  }
}

// prefetch split: issue raw 16B loads now, unpack at use
__device__ inline void ld8_issue(const u16* pb, const float* pf, size_t idx, bool f32, uint4* r2){
  if (f32){
    r2[0] = *(const uint4*)(pf + idx);
    r2[1] = *(const uint4*)(pf + idx + 4);
  } else {
    r2[0] = *(const uint4*)(pb + idx);
  }
}
__device__ inline void ld8_unpack(const uint4* r2, bool f32, float* o){
  if (f32){
    const float* q = (const float*)r2;
    #pragma unroll
    for (int j=0;j<8;j++) o[j] = q[j];
  } else {
    const u32* p = (const u32*)r2;
    #pragma unroll
    for (int j=0;j<8;j++) o[j] = bfu(p[j>>1], j&1);
  }
}

__device__ inline void softmax16(float* l){
  float m = l[0];
  #pragma unroll
  for (int i=1;i<16;i++) m = fmaxf(m, l[i]);
  float s = 0.f;
  #pragma unroll
  for (int i=0;i<16;i++){ l[i] = __expf(l[i]-m); s += l[i]; }
  float r = 1.0f/s;
  #pragma unroll
  for (int i=0;i<16;i++) l[i] *= r;
}

// ---------------------------------------------------------------------------
// convert_all: canonicalize 30 weight tensors to bf16 slots + zero cov.
// grid 32: blocks 0-29 convert, blocks 30-31 zero cov[131072 floats].
// ---------------------------------------------------------------------------
__global__ __launch_bounds__(256) void convert_all(
    const void* img,
    const void* t0, const void* t1, const void* t2, const void* t3,
    const void* t4, const void* t5, const void* t6, const void* t7,
    const void* t8, const void* t9, const void* t10, const void* t11,
    const void* t12, const void* t13, const void* t14, const void* t15,
    const void* t16, const void* t17, const void* t18, const void* t19,
    const void* t20, const void* t21, const void* t22, const void* t23,
    const void* t24, const void* t25, const void* t26, const void* t27,
    const void* t28, const void* t29,
    u16* __restrict__ wc, float* __restrict__ cov)
{
  __shared__ int s_cnt;
  const int t = threadIdx.x;
  const bool f32 = detect_f32(img, t, &s_cnt);
  const int id = blockIdx.x;
  if (id >= 30){
    float4 z; z.x=0.f; z.y=0.f; z.z=0.f; z.w=0.f;
    float4* c4 = (float4*)cov + (size_t)(id-30)*16384;
    for (int j = t; j < 16384; j += 256) c4[j] = z;
    return;
  }
  const int sizes[30] = {4096,4096,4096,4,4096,4096,4096,4,
                         64,64,64,64,64,64,64,64,64,64,64,64,
                         8192,128,8192,64,8192,128,8192,64,4096,4096};
  const void* srcs[30] = {t0,t1,t2,t3,t4,t5,t6,t7,t8,t9,t10,t11,t12,t13,t14,
                          t15,t16,t17,t18,t19,t20,t21,t22,t23,t24,t25,t26,t27,t28,t29};
  const void* s = srcs[id];
  const int n = sizes[id];
  u16* d = wc + (size_t)id*8192;
  for (int j = t; j < n; j += 256)
    d[j] = f32 ? f2bf(((const float*)s)[j]) : ((const u16*)s)[j];
}

// ---------------------------------------------------------------------------
// K1: per-pixel LN of {img, evt, img+evt, img-evt} -> 8 covariance matrices.
// 512 threads = 8 waves; ONE 64x64 Gram per wave (proven round-1 version).
// ---------------------------------------------------------------------------
__global__ __launch_bounds__(512, 4) void k1_cov(
    const void* __restrict__ img, const void* __restrict__ evt,
    const u16* __restrict__ lniw, const u16* __restrict__ lnib,
    const u16* __restrict__ lnew, const u16* __restrict__ lneb,
    const u16* __restrict__ lncw, const u16* __restrict__ lncb,
    const u16* __restrict__ lndw, const u16* __restrict__ lndb,
    float* __restrict__ cov, float* __restrict__ par, int use_par)
{
  __shared__ u16 NtL[4*64*72];
  __shared__ float spart[8][64][5];
  __shared__ float params[8][64];
  __shared__ int s_cnt;

  const int t = threadIdx.x;
  const bool f32 = detect_f32_wide(img, t, &s_cnt);
  const u16* imgb = (const u16*)img; const float* imgf = (const float*)img;
  const u16* evtb = (const u16*)evt; const float* evtf = (const float*)evt;

  const int b = blockIdx.x >> 7;
  const int P0 = (blockIdx.x & 127) * 512;
  const int ch = t >> 3, pg = t & 7;
  const int wave = t >> 6, lane = t & 63, l15 = lane & 15, quad = lane >> 4;

  float wi=bf2f(lniw[ch]), bi=bf2f(lnib[ch]);
  float we=bf2f(lnew[ch]), be=bf2f(lneb[ch]);
  float wc_=bf2f(lncw[ch]), bc_=bf2f(lncb[ch]);
  float wd_=bf2f(lndw[ch]), bd_=bf2f(lndb[ch]);

  const int va = (wave==3)?0 : (wave==7)?1 : (wave<3)?2:3;
  const int vb = (wave==0)?2 : (wave==4)?3 :
                 ((wave==2)||(wave==6)||(wave==7))?1:0;

  float4v acc[4][4];
  #pragma unroll
  for (int i=0;i<4;i++)
    #pragma unroll
    for (int j=0;j<4;j++) acc[i][j]=(float4v)0.f;

  const size_t base = (size_t)(b*64 + ch) * HW;

  for (int it = 0; it < 8; ++it){
    const int p0 = P0 + it*64;
    float A[8], B[8];
    ld8(imgb, imgf, base + p0 + pg*8, f32, A);
    ld8(evtb, evtf, base + p0 + pg*8, f32, B);

    #pragma unroll 1
    for (int jp=0;jp<4;jp++){
      float xa=A[2*jp], xb=A[2*jp+1], ea=B[2*jp], eb=B[2*jp+1];
      float s0a=xa,     s0b=xb;
      float s1a=xa*xa,  s1b=xb*xb;
      float s2a=ea,     s2b=eb;
      float s3a=ea*ea,  s3b=eb*eb;
      float s4a=xa*ea,  s4b=xb*eb;
      #pragma unroll
      for (int m=8;m<=32;m<<=1){
        s0a+=__shfl_xor(s0a,m); s0b+=__shfl_xor(s0b,m);
        s1a+=__shfl_xor(s1a,m); s1b+=__shfl_xor(s1b,m);
        s2a+=__shfl_xor(s2a,m); s2b+=__shfl_xor(s2b,m);
        s3a+=__shfl_xor(s3a,m); s3b+=__shfl_xor(s3b,m);
        s4a+=__shfl_xor(s4a,m); s4b+=__shfl_xor(s4b,m);
      }
      if ((ch&7)==0){
        int px = pg*8 + 2*jp;
        spart[wave][px][0]=s0a; spart[wave][px][1]=s1a; spart[wave][px][2]=s2a;
        spart[wave][px][3]=s3a; spart[wave][px][4]=s4a;
        spart[wave][px+1][0]=s0b; spart[wave][px+1][1]=s1b; spart[wave][px+1][2]=s2b;
        spart[wave][px+1][3]=s3b; spart[wave][px+1][4]=s4b;
      }
    }
    __syncthreads();
    if (t < 64){
      float S0=0,S1=0,S2=0,S3=0,S4=0;
      #pragma unroll
      for (int w=0;w<8;w++){
        S0+=spart[w][t][0]; S1+=spart[w][t][1]; S2+=spart[w][t][2];
        S3+=spart[w][t][3]; S4+=spart[w][t][4];
      }
      const float inv = 0.015625f;
      float mu_i=S0*inv, mu_e=S2*inv;
      float r_i = rsqrtf(fmaf(S1,inv,-mu_i*mu_i)+1e-5f);
      float r_e = rsqrtf(fmaf(S3,inv,-mu_e*mu_e)+1e-5f);
      float mu_c=mu_i+mu_e, mu_d=mu_i-mu_e;
      float r_c = rsqrtf((S1+2.f*S4+S3)*inv - mu_c*mu_c + 1e-5f);
      float r_d = rsqrtf((S1-2.f*S4+S3)*inv - mu_d*mu_d + 1e-5f);
      params[0][t]=mu_i; params[1][t]=r_i; params[2][t]=mu_e; params[3][t]=r_e;
      params[4][t]=mu_c; params[5][t]=r_c; params[6][t]=mu_d; params[7][t]=r_d;
      if (use_par){
        float4 pv; pv.x=mu_i; pv.y=r_i; pv.z=mu_e; pv.w=r_e;
        *(float4*)(par + ((size_t)b*HW + p0 + t)*4) = pv;
      }
    }
    __syncthreads();

    {
      u32 u0[4], u1[4];
      #pragma unroll
      for (int jj=0;jj<4;jj++){
        int px = pg*8 + 2*jj;
        float2 mi01 = *(const float2*)&params[0][px];
        float2 ri01 = *(const float2*)&params[1][px];
        float2 me01 = *(const float2*)&params[2][px];
        float2 re01 = *(const float2*)&params[3][px];
        u0[jj] = packbf2(fmaf((A[2*jj]-mi01.x)*ri01.x, wi, bi),
                         fmaf((A[2*jj+1]-mi01.y)*ri01.y, wi, bi));
        u1[jj] = packbf2(fmaf((B[2*jj]-me01.x)*re01.x, we, be),
                         fmaf((B[2*jj+1]-me01.y)*re01.y, we, be));
      }
      *(uint4*)&NtL[(0*64+ch)*72 + pg*8] = make_uint4(u0[0],u0[1],u0[2],u0[3]);
      *(uint4*)&NtL[(1*64+ch)*72 + pg*8] = make_uint4(u1[0],u1[1],u1[2],u1[3]);
      #pragma unroll
      for (int jj=0;jj<4;jj++){
        int px = pg*8 + 2*jj;
        float2 mc01 = *(const float2*)&params[4][px];
        float2 rc01 = *(const float2*)&params[5][px];
        float2 md01 = *(const float2*)&params[6][px];
        float2 rd01 = *(const float2*)&params[7][px];
        float xc0=A[2*jj]+B[2*jj], xc1=A[2*jj+1]+B[2*jj+1];
        float xd0=A[2*jj]-B[2*jj], xd1=A[2*jj+1]-B[2*jj+1];
        u0[jj] = packbf2(fmaf((xc0-mc01.x)*rc01.x, wc_, bc_),
                         fmaf((xc1-mc01.y)*rc01.y, wc_, bc_));
        u1[jj] = packbf2(fmaf((xd0-md01.x)*rd01.x, wd_, bd_),
                         fmaf((xd1-md01.y)*rd01.y, wd_, bd_));
      }
      *(uint4*)&NtL[(2*64+ch)*72 + pg*8] = make_uint4(u0[0],u0[1],u0[2],u0[3]);
      *(uint4*)&NtL[(3*64+ch)*72 + pg*8] = make_uint4(u1[0],u1[1],u1[2],u1[3]);
    }
    __syncthreads();

    #pragma unroll
    for (int ks=0; ks<2; ks++){
      const int off = ks*32 + quad*8;
      short8 Af[4], Bf[4];
      #pragma unroll
      for (int mi=0;mi<4;mi++){
        Af[mi] = *(const short8*)&NtL[(va*64 + mi*16 + l15)*72 + off];
        Bf[mi] = *(const short8*)&NtL[(vb*64 + mi*16 + l15)*72 + off];
      }
      #pragma unroll
      for (int mi=0;mi<4;mi++)
        #pragma unroll
        for (int nj=0;nj<4;nj++)
          acc[mi][nj] = __builtin_amdgcn_mfma_f32_16x16x32_bf16(Af[mi], Bf[nj], acc[mi][nj], 0,0,0);
    }
  }
  float* cg = cov + ((size_t)wave*NBATCH + b)*4096;
  #pragma unroll
  for (int mi=0;mi<4;mi++)
    #pragma unroll
    for (int nj=0;nj<4;nj++){
      int row0 = mi*16 + quad*4, col = nj*16 + l15;
      #pragma unroll
      for (int r=0;r<4;r++)
        atomicAdd(&cg[(row0+r)*64 + col], acc[mi][nj][r]);
    }
}

// ---------------------------------------------------------------------------
// P2a: T = W @ C  (10 products per batch)
// ---------------------------------------------------------------------------
__global__ __launch_bounds__(256) void p2a(
    const u16* __restrict__ Wq_c, const u16* __restrict__ Wk_c,
    const u16* __restrict__ Wq_d, const u16* __restrict__ Wk_d,
    float* __restrict__ ws)
{
  __shared__ float WL[64][65];
  __shared__ float CL[64][64];
  const int t = threadIdx.x;
  const int b = blockIdx.x & 3;
  const int which = blockIdx.x >> 2;
  int wsel, csel;
  switch (which){
    case 0: wsel=0; csel=0; break;
    case 1: wsel=1; csel=3; break;
    case 2: wsel=1; csel=7; break;
    case 3: wsel=2; csel=4; break;
    case 4: wsel=3; csel=3; break;
    case 5: wsel=3; csel=7; break;
    case 6: wsel=0; csel=1; break;
    case 7: wsel=0; csel=2; break;
    case 8: wsel=2; csel=5; break;
    default: wsel=2; csel=6; break;
  }
  const u16* W = (wsel==0)? Wq_c : (wsel==1)? Wk_c : (wsel==2)? Wq_d : Wk_d;
  const float* Cm = ws + ((size_t)csel*NBATCH + b)*4096;
  { int r = t>>2, c0 = (t&3)*16;
    #pragma unroll
    for (int i=0;i<16;i++) WL[r][c0+i] = bf2f(W[r*64 + c0 + i]);
    const float4* s = (const float4*)(Cm + r*64 + c0);
    float4* d = (float4*)&CL[r][c0];
    d[0]=s[0]; d[1]=s[1]; d[2]=s[2]; d[3]=s[3]; }
  __syncthreads();
  const int r = t>>2, k0 = (t&3)*16;
  float a[16];
  #pragma unroll
  for (int i=0;i<16;i++) a[i]=0.f;
  for (int m=0;m<64;m++){
    float wv = WL[r][m];
    #pragma unroll
    for (int i=0;i<16;i++) a[i] = fmaf(wv, CL[m][k0+i], a[i]);
  }
  float* o = ws + OFF_T + ((size_t)which*NBATCH + b)*4096 + r*64 + k0;
  #pragma unroll
  for (int i=0;i<16;i++) o[i] = a[i];
}

// ---------------------------------------------------------------------------
// P2b: norms, Gram blocks, softmax, A, M = blockdiag(A)@Wv
// ---------------------------------------------------------------------------
__global__ __launch_bounds__(256) void p2b(
    float* __restrict__ ws,
    const u16* __restrict__ Wq_c, const u16* __restrict__ Wk_c,
    const u16* __restrict__ Wq_d, const u16* __restrict__ Wk_d,
    const u16* __restrict__ Wv_c, const u16* __restrict__ Wv_d,
    const u16* __restrict__ temp_c, const u16* __restrict__ temp_d)
{
  const int b = blockIdx.x, t = threadIdx.x;
  __shared__ float rn[6][64];
  __shared__ float GLs[4][64][16];
  __shared__ float AL[3][64][16];
  const float* T = ws + OFF_T;
  {
    int s = t>>6, c = t&63;
    const float* Tp = T + ((size_t)s*NBATCH + b)*4096 + c*64;
    const u16* Wp = (s==0)? Wq_c : (s==3)? Wq_d : Wk_c;
    float acc=0;
    for (int k=0;k<64;k++) acc = fmaf(Tp[k], bf2f(Wp[c*64+k]), acc);
    rn[s][c] = 1.0f/fmaxf(sqrtf(fmaxf(acc,0.f)), 1e-12f);
    if (t < 128){
      int s2 = 4 + (t>>6);
      const float* Tp2 = T + ((size_t)s2*NBATCH + b)*4096 + c*64;
      float acc2=0;
      for (int k=0;k<64;k++) acc2 = fmaf(Tp2[k], bf2f(Wk_d[c*64+k]), acc2);
      rn[s2][c] = 1.0f/fmaxf(sqrtf(fmaxf(acc2,0.f)), 1e-12f);
    }
  }
  #pragma unroll 1
  for (int i=0;i<16;i++){
    int e = t*16 + i;
    int s = e >> 10, c = (e>>4)&63, dl = e&15, d = (c&~15)+dl;
    const float* Tp = T + ((size_t)(6+s)*NBATCH + b)*4096 + c*64;
    const u16* Wp = ((s<2)? Wk_c : Wk_d) + d*64;
    float acc=0;
    for (int j=0;j<64;j++) acc = fmaf(Tp[j], bf2f(Wp[j]), acc);
    GLs[s][c][dl] = acc;
  }
  __syncthreads();
  if (t < 192){
    int set = t>>6, c = t&63, h = c>>4, cb = c&~15;
    if (set == 0){
      float tc = bf2f(temp_c[h]);
      float rq = rn[0][c];
      float l1[16], l2[16];
      #pragma unroll
      for (int dl=0;dl<16;dl++){
        l1[dl] = GLs[0][c][dl]*rq*rn[1][cb+dl]*tc;
        l2[dl] = GLs[1][c][dl]*rq*rn[2][cb+dl]*tc;
      }
      softmax16(l1); softmax16(l2);
      #pragma unroll
      for (int dl=0;dl<16;dl++) AL[0][c][dl] = l1[dl]*l2[dl];
    } else {
      float td = bf2f(temp_d[h]);
      float rq = rn[3][c];
      int gi = (set==1)? 2 : 3;
      int rk = (set==1)? 4 : 5;
      float l[16];
      #pragma unroll
      for (int dl=0;dl<16;dl++) l[dl] = GLs[gi][c][dl]*rq*rn[rk][cb+dl]*td;
      softmax16(l);
      #pragma unroll
      for (int dl=0;dl<16;dl++) AL[set][c][dl] = l[dl];
    }
  }
  __syncthreads();
  for (int wsel=0; wsel<3; wsel++){
    const u16* Wv = (wsel==0)? Wv_c : Wv_d;
    #pragma unroll 1
    for (int i=0;i<16;i++){
      int e = t*16+i, c = e>>6, k = e&63, cb = c&~15;
      float acc=0;
      #pragma unroll
      for (int dl=0;dl<16;dl++) acc = fmaf(AL[wsel][c][dl], bf2f(Wv[(cb+dl)*64 + k]), acc);
      ws[OFF_M + ((size_t)wsel*NBATCH + b)*4096 + c*64 + k] = acc;
    }
  }
}

// ---------------------------------------------------------------------------
// P2c: P = proj @ M  (3 per batch)
// ---------------------------------------------------------------------------
__global__ __launch_bounds__(256) void p2c(
    const u16* __restrict__ proj1, const u16* __restrict__ proj2,
    float* __restrict__ ws)
{
  __shared__ float WL[64][65];
  __shared__ float CL[64][64];
  const int t = threadIdx.x;
  const int b = blockIdx.x & 3;
  const int which = blockIdx.x >> 2;
  const u16* W = (which==0)? proj1 : proj2;
  const float* Cm = ws + OFF_M + ((size_t)which*NBATCH + b)*4096;
  { int r = t>>2, c0 = (t&3)*16;
    #pragma unroll
    for (int i=0;i<16;i++) WL[r][c0+i] = bf2f(W[r*64 + c0 + i]);
    const float4* s = (const float4*)(Cm + r*64 + c0);
    float4* d = (float4*)&CL[r][c0];
    d[0]=s[0]; d[1]=s[1]; d[2]=s[2]; d[3]=s[3]; }
  __syncthreads();
  const int r = t>>2, k0 = (t&3)*16;
  float a[16];
  #pragma unroll
  for (int i=0;i<16;i++) a[i]=0.f;
  for (int m=0;m<64;m++){
    float wv = WL[r][m];
    #pragma unroll
    for (int i=0;i<16;i++) a[i] = fmaf(wv, CL[m][k0+i], a[i]);
  }
  float* o = ws + OFF_P + ((size_t)which*NBATCH + b)*4096 + r*64 + k0;
  #pragma unroll
  for (int i=0;i<16;i++) o[i] = a[i];
}

// ---------------------------------------------------------------------------
// k3 tail (LN over channels + FFN1 + GELU + FFN2 + residual store), with
// compile-time LDS stride so addressing folds to constants per branch.
// ---------------------------------------------------------------------------
template<int STRIDE>
__device__ inline void k3_tail(
    u16* __restrict__ BIG, const u16* __restrict__ fc1L, const u16* __restrict__ fc2L,
    const float* __restrict__ b1L, const float* __restrict__ b2L,
    float4v* acc1, const float* w1r, const float* b1r,
    int wave, int quad, int l15, int px_row,
    void* __restrict__ outp, size_t obase, int b, int px0, bool f32)
{
  float s[4], sq[4];
  #pragma unroll
  for (int j=0;j<4;j++){
    s[j] = acc1[0][j]+acc1[1][j]+acc1[2][j]+acc1[3][j];
    sq[j] = acc1[0][j]*acc1[0][j];
    sq[j] = fmaf(acc1[1][j],acc1[1][j],sq[j]);
    sq[j] = fmaf(acc1[2][j],acc1[2][j],sq[j]);
    sq[j] = fmaf(acc1[3][j],acc1[3][j],sq[j]);
  }
  #pragma unroll
  for (int m=1;m<=8;m<<=1)
    #pragma unroll
    for (int j=0;j<4;j++){ s[j]+=__shfl_xor(s[j],m); sq[j]+=__shfl_xor(sq[j],m); }
  float muj[4], rj[4];
  #pragma unroll
  for (int j=0;j<4;j++){
    muj[j]=s[j]*0.015625f;
    rj[j]=rsqrtf(fmaf(sq[j],0.015625f,-muj[j]*muj[j])+1e-5f);
  }
  #pragma unroll
  for (int nj=0;nj<4;nj++)
    #pragma unroll
    for (int j=0;j<4;j++){
      float tv = (acc1[nj][j]-muj[j])*rj[j];
      tv = fmaf(tv, w1r[nj], b1r[nj]);
      BIG[(wave*16+quad*4+j)*STRIDE + nj*16+l15] = f2bf(tv);
    }
  float4v accF[8];
  #pragma unroll
  for (int nh=0;nh<8;nh++) accF[nh]=(float4v)0.f;
  #pragma unroll
  for (int ks=0;ks<2;ks++){
    const int off = ks*32+quad*8;
    short8 af = *(const short8*)&BIG[px_row*STRIDE + off];
    #pragma unroll
    for (int nh=0;nh<8;nh++){
      short8 bw = *(const short8*)&fc1L[(nh*16+l15)*72 + off];
      accF[nh] = __builtin_amdgcn_mfma_f32_16x16x32_bf16(af, bw, accF[nh], 0,0,0);
    }
  }
  #pragma unroll
  for (int nh=0;nh<8;nh++){
    float bb = b1L[nh*16+l15];
    #pragma unroll
    for (int j=0;j<4;j++){
      float v = accF[nh][j] + bb;
      float g2 = 0.5f*v*(1.0f + erff(v*0.70710678118654752f));
      BIG[(wave*16+quad*4+j)*STRIDE + nh*16+l15] = f2bf(g2);
    }
  }
  float4v accO[4];
  #pragma unroll
  for (int nj=0;nj<4;nj++) accO[nj]=(float4v)0.f;
  #pragma unroll
  for (int ks=0;ks<4;ks++){
    const int off = ks*32+quad*8;
    short8 ag = *(const short8*)&BIG[px_row*STRIDE + off];
    #pragma unroll
    for (int nj=0;nj<4;nj++){
      short8 bw = *(const short8*)&fc2L[(nj*16+l15)*136 + off];
      accO[nj] = __builtin_amdgcn_mfma_f32_16x16x32_bf16(ag, bw, accO[nj], 0,0,0);
    }
  }
  #pragma unroll
  for (int nj=0;nj<4;nj++){
    float bb = b2L[nj*16+l15];
    int r = nj*16+l15;
    float v0 = acc1[nj][0] + accO[nj][0] + bb;
    float v1 = acc1[nj][1] + accO[nj][1] + bb;
    float v2 = acc1[nj][2] + accO[nj][2] + bb;
    float v3 = acc1[nj][3] + accO[nj][3] + bb;
    size_t oi = obase + (size_t)(b*64 + r)*HW + px0;
    if (f32){ float4 fv; fv.x=v0; fv.y=v1; fv.z=v2; fv.w=v3;
      *(float4*)((float*)outp + oi) = fv; }
    else *(uint2*)((u16*)outp + oi) = make_uint2(packbf2(v0,v1), packbf2(v2,v3));
  }
}

// ---------------------------------------------------------------------------
// K3 fat v2: one dispatch, both branches, XCD-correct pairing.
// bid -> {isdiff=(bid>>3)&1, slab=(bid&7)|((bid>>4)<<3)}: pair members differ
// by exactly 8 in dispatch index -> SAME XCD (bid%8 invariant), adjacent in
// dispatch order -> the pair's img/evt/par slab reads share the XCD's L2.
// Bodies = round-4 proven versions (incl. next-iter prefetch); tail is
// templated on LDS stride (136 common / 144 diff) for constant addressing.
// ---------------------------------------------------------------------------
__global__ __launch_bounds__(256, 2) void k3_fat2(
    const void* __restrict__ img, const void* __restrict__ evt,
    const u16* __restrict__ lniw, const u16* __restrict__ lnib,
    const u16* __restrict__ lnew, const u16* __restrict__ lneb,
    const u16* __restrict__ ln1w, const u16* __restrict__ ln1b,
    const u16* __restrict__ ln2w, const u16* __restrict__ ln2b,
    const u16* __restrict__ fc1cw, const u16* __restrict__ fc1cb,
    const u16* __restrict__ fc2cw, const u16* __restrict__ fc2cb,
    const u16* __restrict__ fc1dw, const u16* __restrict__ fc1db,
    const u16* __restrict__ fc2dw, const u16* __restrict__ fc2db,
    const float* __restrict__ Pmat, void* __restrict__ outp,
    const float* __restrict__ par, int use_par)
{
  __shared__ __align__(16) u16 POOL[36352];   // 72704 B
  __shared__ float spart[4][64][4];
  __shared__ float params[64][4];
  __shared__ float b1L[128];
  __shared__ float b2L[64];
  __shared__ int s_cnt;

  u16* fc1L = POOL;            // 128*72
  u16* fc2L = POOL + 9216;     // 64*136
  u16* P0L  = POOL + 17920;    // 64*72 (Pc / Pi)
  u16* P1L  = POOL + 22528;    // 64*72 (Pe)
  u16* BIG  = POOL + 27136;    // 64*144 max (SB stride 136 / N2L stride 144)

  const int t = threadIdx.x;
  const bool f32 = detect_f32(img, t, &s_cnt);
  const u16* imgb = (const u16*)img; const float* imgf = (const float*)img;
  const u16* evtb = (const u16*)evt; const float* evtf = (const float*)evt;

  // XCD-correct pairing: (bid, bid+8) process the SAME slab on the SAME XCD.
  const int bid = blockIdx.x;
  const int isdiff = (bid >> 3) & 1;
  const int slab = (bid & 7) | ((bid >> 4) << 3);   // 0..1023, bijective
  const int b = slab >> 8;
  const int P0 = (slab & 255) * 256;
  const size_t obase = isdiff ? (size_t)16777216 : (size_t)0;
  const int chg = t >> 3, pg = t & 7, ch0 = chg*2;
  const int wave = t >> 6, lane = t & 63, l15 = lane & 15, quad = lane >> 4;

  const u16* fc1w = isdiff ? fc1dw : fc1cw;
  const u16* fc1b = isdiff ? fc1db : fc1cb;
  const u16* fc2w = isdiff ? fc2dw : fc2cw;
  const u16* fc2b = isdiff ? fc2db : fc2cb;
  const u16* lnfw = isdiff ? ln2w : ln1w;
  const u16* lnfb = isdiff ? ln2b : ln1b;

  { int row = t >> 1, c0 = (t & 1)*32;
    const uint4* s = (const uint4*)(fc1w + row*64 + c0);
    uint4* d = (uint4*)&fc1L[row*72 + c0];
    d[0]=s[0]; d[1]=s[1]; d[2]=s[2]; d[3]=s[3]; }
  { int row = t >> 2, c0 = (t & 3)*32;
    const uint4* s = (const uint4*)(fc2w + row*128 + c0);
    uint4* d = (uint4*)&fc2L[row*136 + c0];
    d[0]=s[0]; d[1]=s[1]; d[2]=s[2]; d[3]=s[3]; }
  if (!isdiff){
    int row = t >> 2, c0 = (t & 3)*16;
    const float* s = Pmat + (size_t)b*4096 + row*64 + c0;
    u32 u[8];
    #pragma unroll
    for (int i=0;i<8;i++) u[i] = packbf2(s[2*i], s[2*i+1]);
    uint4* d = (uint4*)&P0L[row*72 + c0];
    d[0] = make_uint4(u[0],u[1],u[2],u[3]);
    d[1] = make_uint4(u[4],u[5],u[6],u[7]);
  } else {
    int row = t >> 2, c0 = (t & 3)*16;
    const float* si_ = Pmat + ((size_t)1*NBATCH + b)*4096 + row*64 + c0;
    const float* se_ = Pmat + ((size_t)2*NBATCH + b)*4096 + row*64 + c0;
    u32 u[8];
    #pragma unroll
    for (int i=0;i<8;i++) u[i] = packbf2(si_[2*i], si_[2*i+1]);
    uint4* d = (uint4*)&P0L[row*72 + c0];
    d[0] = make_uint4(u[0],u[1],u[2],u[3]); d[1] = make_uint4(u[4],u[5],u[6],u[7]);
    #pragma unroll
    for (int i=0;i<8;i++) u[i] = packbf2(se_[2*i], se_[2*i+1]);
    uint4* d2 = (uint4*)&P1L[row*72 + c0];
    d2[0] = make_uint4(u[0],u[1],u[2],u[3]); d2[1] = make_uint4(u[4],u[5],u[6],u[7]);
  }
  if (t < 128) b1L[t] = bf2f(fc1b[t]);
  if (t < 64)  b2L[t] = bf2f(fc2b[t]);

  float wi0=bf2f(lniw[ch0]), wi1=bf2f(lniw[ch0+1]);
  float we0=bf2f(lnew[ch0]), we1=bf2f(lnew[ch0+1]);
  float bi0=bf2f(lnib[ch0]), bi1=bf2f(lnib[ch0+1]);
  float be0=bf2f(lneb[ch0]), be1=bf2f(lneb[ch0+1]);
  float bs0=bi0+be0, bs1=bi1+be1;
  float w1r[4], b1r[4];
  #pragma unroll
  for (int nj=0;nj<4;nj++){ w1r[nj]=bf2f(lnfw[nj*16+l15]); b1r[nj]=bf2f(lnfb[nj*16+l15]); }

  const size_t base_i = (size_t)(b*64 + ch0)*HW;
  uint4 rA0[2], rA1[2], rB0[2], rB1[2];
  float4 PR[8];
  if (use_par){
    ld8_issue(imgb, imgf, base_i + P0 + pg*8, f32, rA0);
    ld8_issue(imgb, imgf, base_i + HW + P0 + pg*8, f32, rA1);
    ld8_issue(evtb, evtf, base_i + P0 + pg*8, f32, rB0);
    ld8_issue(evtb, evtf, base_i + HW + P0 + pg*8, f32, rB1);
    const float4* pp = (const float4*)(par + ((size_t)b*HW + P0 + pg*8)*4);
    #pragma unroll
    for (int j=0;j<8;j++) PR[j] = pp[j];
  }
  __syncthreads();

  for (int it=0; it<4; ++it){
    const int p0 = P0 + it*64;
    // ---- n-hat production into BIG ----
    if (use_par){
      float A0[8], A1[8], B0[8], B1[8];
      ld8_unpack(rA0, f32, A0); ld8_unpack(rA1, f32, A1);
      ld8_unpack(rB0, f32, B0); ld8_unpack(rB1, f32, B1);
      if (!isdiff){
        #pragma unroll
        for (int j=0;j<8;j++){
          float4 pr = PR[j];
          float a0=(A0[j]-pr.x)*pr.y, a1=(A1[j]-pr.x)*pr.y;
          float c0f=(B0[j]-pr.z)*pr.w, c1f=(B1[j]-pr.z)*pr.w;
          float n0 = fmaf(a0, wi0, fmaf(c0f, we0, bs0));
          float n1 = fmaf(a1, wi1, fmaf(c1f, we1, bs1));
          *(u32*)&BIG[(pg*8+j)*136 + ch0] = packbf2(n0, n1);
        }
      } else {
        #pragma unroll
        for (int j=0;j<8;j++){
          float4 pr = PR[j];
          float a0=(A0[j]-pr.x)*pr.y, a1=(A1[j]-pr.x)*pr.y;
          float c0f=(B0[j]-pr.z)*pr.w, c1f=(B1[j]-pr.z)*pr.w;
          *(u32*)&BIG[(pg*8+j)*144 + ch0]      = packbf2(fmaf(a0,wi0,bi0), fmaf(a1,wi1,bi1));
          *(u32*)&BIG[(pg*8+j)*144 + 72 + ch0] = packbf2(fmaf(c0f,we0,be0), fmaf(c1f,we1,be1));
        }
      }
    } else {
      float A0[8], A1[8], B0[8], B1[8];
      ld8(imgb, imgf, base_i + p0 + pg*8, f32, A0);
      ld8(imgb, imgf, base_i + HW + p0 + pg*8, f32, A1);
      ld8(evtb, evtf, base_i + p0 + pg*8, f32, B0);
      ld8(evtb, evtf, base_i + HW + p0 + pg*8, f32, B1);
      float si[8], sii[8], se[8], see[8];
      #pragma unroll
      for (int j=0;j<8;j++){
        float xi0=A0[j], xi1=A1[j], xe0=B0[j], xe1=B1[j];
        si[j]=xi0+xi1; sii[j]=fmaf(xi0,xi0,xi1*xi1);
        se[j]=xe0+xe1; see[j]=fmaf(xe0,xe0,xe1*xe1);
      }
      #pragma unroll
      for (int m=8;m<=32;m<<=1)
        #pragma unroll
        for (int j=0;j<8;j++){
          si[j]+=__shfl_xor(si[j],m); sii[j]+=__shfl_xor(sii[j],m);
          se[j]+=__shfl_xor(se[j],m); see[j]+=__shfl_xor(see[j],m);
        }
      if ((chg&7)==0){
        #pragma unroll
        for (int j=0;j<8;j++){
          spart[wave][pg*8+j][0]=si[j]; spart[wave][pg*8+j][1]=sii[j];
          spart[wave][pg*8+j][2]=se[j]; spart[wave][pg*8+j][3]=see[j];
        }
      }
      __syncthreads();
      if (t<64){
        float S0=0,S1=0,S2=0,S3=0;
        #pragma unroll
        for (int w=0;w<4;w++){ S0+=spart[w][t][0]; S1+=spart[w][t][1]; S2+=spart[w][t][2]; S3+=spart[w][t][3]; }
        const float inv=0.015625f;
        float mu_i=S0*inv, mu_e=S2*inv;
        float r_i=rsqrtf(fmaf(S1,inv,-mu_i*mu_i)+1e-5f);
        float r_e=rsqrtf(fmaf(S3,inv,-mu_e*mu_e)+1e-5f);
        params[t][0]=mu_i; params[t][1]=r_i; params[t][2]=mu_e; params[t][3]=r_e;
      }
      __syncthreads();
      if (!isdiff){
        #pragma unroll
        for (int j=0;j<8;j++){
          float4 pr = *(const float4*)&params[pg*8+j][0];
          float a0=(A0[j]-pr.x)*pr.y, a1=(A1[j]-pr.x)*pr.y;
          float c0f=(B0[j]-pr.z)*pr.w, c1f=(B1[j]-pr.z)*pr.w;
          float n0 = fmaf(a0, wi0, fmaf(c0f, we0, bs0));
          float n1 = fmaf(a1, wi1, fmaf(c1f, we1, bs1));
          *(u32*)&BIG[(pg*8+j)*136 + ch0] = packbf2(n0, n1);
        }
      } else {
        #pragma unroll
        for (int j=0;j<8;j++){
          float4 pr = *(const float4*)&params[pg*8+j][0];
          float a0=(A0[j]-pr.x)*pr.y, a1=(A1[j]-pr.x)*pr.y;
          float c0f=(B0[j]-pr.z)*pr.w, c1f=(B1[j]-pr.z)*pr.w;
          *(u32*)&BIG[(pg*8+j)*144 + ch0]      = packbf2(fmaf(a0,wi0,bi0), fmaf(a1,wi1,bi1));
          *(u32*)&BIG[(pg*8+j)*144 + 72 + ch0] = packbf2(fmaf(c0f,we0,be0), fmaf(c1f,we1,be1));
        }
      }
    }
    __syncthreads();
    // issue next-iter raw loads: drained at END barrier, hidden under compute
    if (use_par && it < 3){
      const int pn = p0 + 64;
      ld8_issue(imgb, imgf, base_i + pn + pg*8, f32, rA0);
      ld8_issue(imgb, imgf, base_i + HW + pn + pg*8, f32, rA1);
      ld8_issue(evtb, evtf, base_i + pn + pg*8, f32, rB0);
      ld8_issue(evtb, evtf, base_i + HW + pn + pg*8, f32, rB1);
      const float4* pp = (const float4*)(par + ((size_t)b*HW + pn + pg*8)*4);
      #pragma unroll
      for (int j=0;j<8;j++) PR[j] = pp[j];
    }
    // ---- GEMM1 + tail (constant strides per branch) ----
    float4v acc1[4];
    #pragma unroll
    for (int nj=0;nj<4;nj++) acc1[nj]=(float4v)0.f;
    const int px_row = wave*16 + l15;
    const int px0 = p0 + wave*16 + quad*4;
    if (!isdiff){
      #pragma unroll
      for (int ks=0;ks<2;ks++){
        const int off = ks*32 + quad*8;
        short8 af = *(const short8*)&BIG[px_row*136 + off];
        #pragma unroll
        for (int nj=0;nj<4;nj++){
          short8 bw = *(const short8*)&P0L[(nj*16+l15)*72 + off];
          acc1[nj] = __builtin_amdgcn_mfma_f32_16x16x32_bf16(af, bw, acc1[nj], 0,0,0);
        }
      }
      k3_tail<136>(BIG, fc1L, fc2L, b1L, b2L, acc1, w1r, b1r,
                   wave, quad, l15, px_row, outp, obase, b, px0, f32);
    } else {
      #pragma unroll
      for (int ks=0;ks<2;ks++){
        const int off = ks*32 + quad*8;
        short8 ai = *(const short8*)&BIG[px_row*144 + off];
        short8 ae = *(const short8*)&BIG[px_row*144 + 72 + off];
        #pragma unroll
        for (int nj=0;nj<4;nj++){
          short8 bwi = *(const short8*)&P0L[(nj*16+l15)*72 + off];
          acc1[nj] = __builtin_amdgcn_mfma_f32_16x16x32_bf16(ai, bwi, acc1[nj], 0,0,0);
          short8 bwe = *(const short8*)&P1L[(nj*16+l15)*72 + off];
          acc1[nj] = __builtin_amdgcn_mfma_f32_16x16x32_bf16(ae, bwe, acc1[nj], 0,0,0);
        }
      }
      k3_tail<144>(BIG, fc1L, fc2L, b1L, b2L, acc1, w1r, b1r,
                   wave, quad, l15, px_row, outp, obase, b, px0, f32);
    }
    __syncthreads();   // protects BIG + drains prefetch loads (hidden by compute)
  }
}

extern "C" void kernel_launch(void* const* d_in, const int* in_sizes, int n_in,
                              void* d_out, int out_size, void* d_ws, size_t ws_size,
                              hipStream_t stream)
{
  const void* img = d_in[0];
  const void* evt = d_in[1];
  float* ws = (float*)d_ws;
  u16* wc = (u16*)(ws + OFF_WC);
  float* par = ws + OFF_PAR;
  const int use_par = (ws_size >= WS_NEED) ? 1 : 0;
  #define SLOT(i) (wc + (size_t)((i)-2)*8192)

  convert_all<<<dim3(32), dim3(256), 0, stream>>>(img,
      d_in[2], d_in[3], d_in[4], d_in[5], d_in[6], d_in[7], d_in[8], d_in[9],
      d_in[10], d_in[11], d_in[12], d_in[13], d_in[14], d_in[15], d_in[16], d_in[17],
      d_in[18], d_in[19], d_in[20], d_in[21], d_in[22], d_in[23], d_in[24], d_in[25],
      d_in[26], d_in[27], d_in[28], d_in[29], d_in[30], d_in[31], wc, ws);
  k1_cov<<<dim3(512), dim3(512), 0, stream>>>(img, evt,
      SLOT(10), SLOT(11), SLOT(12), SLOT(13), SLOT(14), SLOT(15), SLOT(16), SLOT(17),
      ws, par, use_par);
  p2a<<<dim3(40), dim3(256), 0, stream>>>(SLOT(2), SLOT(3), SLOT(6), SLOT(7), ws);
  p2b<<<dim3(4), dim3(256), 0, stream>>>(ws, SLOT(2), SLOT(3), SLOT(6), SLOT(7),
      SLOT(4), SLOT(8), SLOT(5), SLOT(9));
  p2c<<<dim3(12), dim3(256), 0, stream>>>(SLOT(30), SLOT(31), ws);
  k3_fat2<<<dim3(2048), dim3(256), 0, stream>>>(img, evt,
      SLOT(10), SLOT(11), SLOT(12), SLOT(13),
      SLOT(18), SLOT(19), SLOT(20), SLOT(21),
      SLOT(22), SLOT(23), SLOT(24), SLOT(25),
      SLOT(26), SLOT(27), SLOT(28), SLOT(29),
      ws + OFF_P, d_out, par, use_par);
  #undef SLOT
}